// Round 7
// baseline (679.794 us; speedup 1.0000x reference)
//
#include <hip/hip_runtime.h>
#include <math.h>

// Problem constants
#define TEMP 0.7f
#define TOPK 50
#define TOPP 0.9f
#define M_TOT 2048      // B*S
#define K_DIM 512       // H
#define V_DIM 50257     // vocab
#define KP 1536         // 3*K_DIM: [hi|hi|lo] x [hi|lo|hi]

// 256^2 8-phase GEMM geometry
#define BM2 256
#define BN2 256
#define BK2 64
#define NPAD2 50432          // 197*256
#define NBN2 (NPAD2 / BN2)   // 197 N-tiles
#define NBM2 (M_TOT / BM2)   // 8 M-tiles
#define NKT (KP / BK2)       // 24 K-tiles
#define NIT (NKT / 2)        // 12 iterations (2 K-tiles each)
#define NBH (NPAD2 / 128)    // 394 half-tiles for Tmax

typedef short s16x8 __attribute__((ext_vector_type(8)));
typedef float f32x4 __attribute__((ext_vector_type(4)));

#define MFMA_16x16x32_BF16(acc, va, vb) \
  asm("v_mfma_f32_16x16x32_bf16 %0, %1, %2, %0" : "+v"(acc) : "v"(va), "v"(vb))

__device__ __forceinline__ unsigned short bf16_rn(float x) {
  unsigned u = __float_as_uint(x);
  unsigned r = u + 0x7FFFu + ((u >> 16) & 1u);
  return (unsigned short)(r >> 16);
}
__device__ __forceinline__ float bf16_to_f(unsigned short h) {
  return __uint_as_float(((unsigned)h) << 16);
}
__device__ __forceinline__ unsigned f2key(float f) {
  unsigned u = __float_as_uint(f);
  return (u & 0x80000000u) ? ~u : (u | 0x80000000u);
}

// ---------------- conversion: X -> [hi|hi|lo], W -> [hi|lo|hi] ----------------
__global__ __launch_bounds__(256) void convx_kernel(const float* __restrict__ X,
                                                    unsigned short* __restrict__ Xp) {
  int idx = blockIdx.x * 256 + threadIdx.x;
  const int total = M_TOT * (K_DIM / 4);
  if (idx >= total) return;
  int row = idx >> 7;
  int q = idx & 127;
  const float4 v = reinterpret_cast<const float4*>(X)[idx];
  float vv[4] = {v.x, v.y, v.z, v.w};
  unsigned short hi[4], lo[4];
#pragma unroll
  for (int j = 0; j < 4; ++j) {
    hi[j] = bf16_rn(vv[j]);
    lo[j] = bf16_rn(vv[j] - bf16_to_f(hi[j]));
  }
  ushort4 h4 = make_ushort4(hi[0], hi[1], hi[2], hi[3]);
  ushort4 l4 = make_ushort4(lo[0], lo[1], lo[2], lo[3]);
  size_t base = (size_t)row * KP + q * 4;
  *reinterpret_cast<ushort4*>(Xp + base) = h4;
  *reinterpret_cast<ushort4*>(Xp + base + K_DIM) = h4;
  *reinterpret_cast<ushort4*>(Xp + base + 2 * K_DIM) = l4;
}

__global__ __launch_bounds__(256) void convw_kernel(const float* __restrict__ W,
                                                    unsigned short* __restrict__ Wp) {
  int idx = blockIdx.x * 256 + threadIdx.x;
  const int total = NPAD2 * (K_DIM / 4);
  if (idx >= total) return;
  int row = idx >> 7;
  int q = idx & 127;
  float4 v = make_float4(0.f, 0.f, 0.f, 0.f);
  if (row < V_DIM) v = reinterpret_cast<const float4*>(W)[(size_t)row * 128 + q];
  float vv[4] = {v.x, v.y, v.z, v.w};
  unsigned short hi[4], lo[4];
#pragma unroll
  for (int j = 0; j < 4; ++j) {
    hi[j] = bf16_rn(vv[j]);
    lo[j] = bf16_rn(vv[j] - bf16_to_f(hi[j]));
  }
  ushort4 h4 = make_ushort4(hi[0], hi[1], hi[2], hi[3]);
  ushort4 l4 = make_ushort4(lo[0], lo[1], lo[2], lo[3]);
  size_t base = (size_t)row * KP + q * 4;
  *reinterpret_cast<ushort4*>(Wp + base) = h4;
  *reinterpret_cast<ushort4*>(Wp + base + K_DIM) = l4;
  *reinterpret_cast<ushort4*>(Wp + base + 2 * K_DIM) = h4;
}

// ---------------- 256x256 8-phase MFMA GEMM (T3+T4+T5) ----------------
// 512 threads = 8 waves (2M x 4N); per-wave output 128x64 = 8x4 frags.
// LDS 128 KiB: slot s at s*64K: A-tile [0,32K), B-tile [32K,64K).
// Tile layout: 256 rows x 128 B (BK=64 bf16), XOR swizzle byte^=(row&7)<<4.
// Per phase: ds-reads || 1 half-tile stage -> barrier -> lgkm(0) -> 16 MFMA -> barrier.
// vmcnt(2) before the trailing barrier of phases 3 and 7 (counted, never 0 mid-loop).

#define QUAD(A, B, MH, NH)                                                   \
  do {                                                                       \
    __builtin_amdgcn_s_setprio(1);                                           \
    _Pragma("unroll") for (int fi = 0; fi < 4; ++fi)                         \
        _Pragma("unroll") for (int fj = 0; fj < 2; ++fj)                     \
        _Pragma("unroll") for (int kk = 0; kk < 2; ++kk)                     \
            MFMA_16x16x32_BF16(acc[(MH)*4 + fi][(NH)*2 + fj], A[fi][kk],     \
                               B[fj][kk]);                                   \
    __builtin_amdgcn_s_setprio(0);                                           \
  } while (0)

#define MIDBAR()                                        \
  do {                                                  \
    __builtin_amdgcn_s_barrier();                       \
    asm volatile("s_waitcnt lgkmcnt(0)" ::: "memory");  \
    __builtin_amdgcn_sched_barrier(0);                  \
  } while (0)

__global__ __launch_bounds__(512, 2) void gemm256_kernel(
    const unsigned short* __restrict__ Ap, const unsigned short* __restrict__ Bp,
    const float* __restrict__ Bv, float* __restrict__ C,
    unsigned* __restrict__ Tmax) {
  __shared__ __align__(16) unsigned char lds[131072];
  const int tid = threadIdx.x;
  const int w = tid >> 6, lane = tid & 63;
  const int wr = w >> 2, wc = w & 3;
  const int bm = blockIdx.x * BM2, bn = blockIdx.y * BN2;

  f32x4 acc[8][4] = {};
  s16x8 a[4][2], b0[2][2], b1[2][2];

  // stage one 16KB half-tile: part 0=A.h0 1=A.h1 2=B.h0 3=B.h1
  auto STAGE = [&](int kt, int part) {
    if (kt >= NKT) return;
    const int mat = part >> 1, half = part & 1;
    unsigned char* base = lds + ((kt & 1) << 16) + (mat << 15);
    const unsigned short* src = mat ? Bp : Ap;
    const int rb = mat ? bn : bm;
#pragma unroll
    for (int l = 0; l < 2; ++l) {
      int pp = (half << 14) + ((l * 512 + tid) << 4);
      int row = pp >> 7;
      int cb = (pp & 127) ^ ((row & 7) << 4);
      const unsigned short* g = src + (size_t)(rb + row) * KP + kt * BK2 + (cb >> 1);
      __builtin_amdgcn_global_load_lds(
          (const __attribute__((address_space(1))) unsigned int*)g,
          (__attribute__((address_space(3))) unsigned int*)(base + pp), 16, 0, 0);
    }
  };
  auto LDA = [&](int slot, int mh) {
    const unsigned char* base = lds + (slot << 16);
#pragma unroll
    for (int fi = 0; fi < 4; ++fi)
#pragma unroll
      for (int kk = 0; kk < 2; ++kk) {
        int row = (wr << 7) + (mh << 6) + (fi << 4) + (lane & 15);
        int kbyte = (kk << 6) + ((lane >> 4) << 4);
        a[fi][kk] = *reinterpret_cast<const s16x8*>(
            base + (row << 7) + (kbyte ^ ((row & 7) << 4)));
      }
  };
  auto LDB = [&](s16x8 (&b)[2][2], int slot, int nh) {
    const unsigned char* base = lds + (slot << 16) + 32768;
#pragma unroll
    for (int fj = 0; fj < 2; ++fj)
#pragma unroll
      for (int kk = 0; kk < 2; ++kk) {
        int col = (wc << 6) + (nh << 5) + (fj << 4) + (lane & 15);
        int kbyte = (kk << 6) + ((lane >> 4) << 4);
        b[fj][kk] = *reinterpret_cast<const s16x8*>(
            base + (col << 7) + (kbyte ^ ((col & 7) << 4)));
      }
  };

  // prologue: K-tile 0 fully + (1).A.h0; wait all but last stage; sync
  STAGE(0, 0); STAGE(0, 1); STAGE(0, 2); STAGE(0, 3); STAGE(1, 0);
  asm volatile("s_waitcnt vmcnt(2)" ::: "memory");
  __builtin_amdgcn_s_barrier();
  __builtin_amdgcn_sched_barrier(0);

  for (int t = 0; t < NIT; ++t) {
    const int k0 = 2 * t;      // slot0 K-tile
    const int k1 = 2 * t + 1;  // slot1 K-tile
    // ---- phase 0: (mh0,nh0) of k0
    LDA(0, 0); LDB(b0, 0, 0);
    STAGE(k1, 1);
    MIDBAR();
    QUAD(a, b0, 0, 0);
    __builtin_amdgcn_s_barrier();
    // ---- phase 1: (mh0,nh1)
    LDB(b1, 0, 1);
    STAGE(k1, 2);
    MIDBAR();
    QUAD(a, b1, 0, 1);
    __builtin_amdgcn_s_barrier();
    // ---- phase 2: (mh1,nh0)
    LDA(0, 1);
    STAGE(k1, 3);
    MIDBAR();
    QUAD(a, b0, 1, 0);
    __builtin_amdgcn_s_barrier();
    // ---- phase 3: (mh1,nh1); slot0 free after phase 2 -> stage (k0+2).A.h0
    STAGE(k0 + 2, 0);
    MIDBAR();
    QUAD(a, b1, 1, 1);
    if (t < NIT - 1) asm volatile("s_waitcnt vmcnt(2)" ::: "memory");
    else             asm volatile("s_waitcnt vmcnt(0)" ::: "memory");
    __builtin_amdgcn_s_barrier();
    __builtin_amdgcn_sched_barrier(0);
    // ---- phase 4: (mh0,nh0) of k1
    LDA(1, 0); LDB(b0, 1, 0);
    STAGE(k0 + 2, 1);
    MIDBAR();
    QUAD(a, b0, 0, 0);
    __builtin_amdgcn_s_barrier();
    // ---- phase 5: (mh0,nh1)
    LDB(b1, 1, 1);
    STAGE(k0 + 2, 2);
    MIDBAR();
    QUAD(a, b1, 0, 1);
    __builtin_amdgcn_s_barrier();
    // ---- phase 6: (mh1,nh0)
    LDA(1, 1);
    STAGE(k0 + 2, 3);
    MIDBAR();
    QUAD(a, b0, 1, 0);
    __builtin_amdgcn_s_barrier();
    // ---- phase 7: (mh1,nh1); slot1 free after phase 6 -> stage (k1+2).A.h0
    STAGE(k1 + 2, 0);
    MIDBAR();
    QUAD(a, b1, 1, 1);
    if (t < NIT - 1) asm volatile("s_waitcnt vmcnt(2)" ::: "memory");
    else             asm volatile("s_waitcnt vmcnt(0)" ::: "memory");
    __builtin_amdgcn_s_barrier();
    __builtin_amdgcn_sched_barrier(0);
  }

  // ---------------- epilogue: C write + per-(row, 128-col-half) max ----------------
  __syncthreads();
  unsigned* umax = (unsigned*)lds;  // 256 rows x 2 halves
  umax[tid] = 0;
  __syncthreads();

  const int h = wc >> 1;  // this wave's 128-col half
#pragma unroll
  for (int i = 0; i < 8; ++i) {
    float mx[4];
#pragma unroll
    for (int r = 0; r < 4; ++r) mx[r] = -INFINITY;
#pragma unroll
    for (int j = 0; j < 4; ++j) {
      int n = bn + (wc << 6) + (j << 4) + (lane & 15);
      if (n < V_DIM) {
        float bv = Bv[n];
#pragma unroll
        for (int r = 0; r < 4; ++r) {
          int m = bm + (wr << 7) + (i << 4) + ((lane >> 4) << 2) + r;
          float val = (acc[i][j][r] + bv) / TEMP;
          C[(size_t)m * V_DIM + n] = val;
          mx[r] = fmaxf(mx[r], val);
        }
      }
    }
#pragma unroll
    for (int r = 0; r < 4; ++r) {
      float v = mx[r];
      v = fmaxf(v, __shfl_xor(v, 1));
      v = fmaxf(v, __shfl_xor(v, 2));
      v = fmaxf(v, __shfl_xor(v, 4));
      v = fmaxf(v, __shfl_xor(v, 8));
      if ((lane & 15) == 0) {
        int lrow = (wr << 7) + (i << 4) + ((lane >> 4) << 2) + r;
        atomicMax(&umax[lrow * 2 + h], f2key(v));
      }
    }
  }
  __syncthreads();
  {
    int lrow = tid >> 1, hh = tid & 1;
    Tmax[(size_t)(bm + lrow) * NBH + blockIdx.y * 2 + hh] = umax[tid];
  }
}

// ---- per-row select: Tmax-guided gather + pure-write zero ----
#define CAP 1024
#define SCAP 256

__global__ __launch_bounds__(256) void select_kernel(float* __restrict__ C,
                                                     const unsigned* __restrict__ Tmax) {
  const int row = blockIdx.x;
  float* rowp = C + (size_t)row * V_DIM;
  const int tid = threadIdx.x;

  __shared__ unsigned tk[NBH];
  __shared__ short ctile[NBH];
  __shared__ unsigned s_t50;
  __shared__ float cval[CAP];
  __shared__ int cidx[CAP];
  __shared__ float sval[SCAP];
  __shared__ int sidx[SCAP];
  __shared__ float pvals[SCAP];
  __shared__ int s_cnt, s_ntile, s_nsurv, s_kc;
  __shared__ float s_invZ;

  for (int i = tid; i < NBH; i += 256) tk[i] = Tmax[(size_t)row * NBH + i];
  if (tid == 0) { s_cnt = 0; s_ntile = 0; s_nsurv = 0; }
  __syncthreads();
  for (int i = tid; i < NBH; i += 256) {
    unsigned ki = tk[i];
    int r = 0;
    for (int j = 0; j < NBH; ++j) {
      unsigned kj = tk[j];
      r += (kj > ki) || (kj == ki && j < i);
    }
    if (r == TOPK - 1) s_t50 = ki;
  }
  __syncthreads();
  const unsigned t50 = s_t50;

  for (int i = tid; i < NBH; i += 256) {
    if (tk[i] >= t50) {
      int p = atomicAdd(&s_ntile, 1);
      ctile[p] = (short)i;
    }
  }
  __syncthreads();
  const int ntile = s_ntile;

  for (int e = tid; e < ntile * 128; e += 256) {
    int ti = ctile[e >> 7];
    int n = ti * 128 + (e & 127);
    if (n < V_DIM) {
      float l = rowp[n];
      if (f2key(l) >= t50) {
        int p = atomicAdd(&s_cnt, 1);
        if (p < CAP) { cval[p] = l; cidx[p] = n; }
      }
    }
  }
  __syncthreads();
  const int n = min(s_cnt, CAP);

  // zero the whole row: pure stream write
  {
    const float4 z4 = make_float4(0.f, 0.f, 0.f, 0.f);
    const int NQ = V_DIM >> 2;
    for (int q = tid; q < NQ; q += 256) reinterpret_cast<float4*>(rowp)[q] = z4;
    if (tid == 0) rowp[V_DIM - 1] = 0.f;
  }

  // parallel stable rank (val desc, idx asc)
  for (int i = tid; i < n; i += 256) {
    float vi = cval[i];
    int xi = cidx[i];
    int r = 0;
    for (int j = 0; j < n; ++j) {
      float vj = cval[j];
      if (vj > vi || (vj == vi && cidx[j] < xi)) ++r;
    }
    if (r < SCAP) { sval[r] = vi; sidx[r] = xi; }
  }
  __syncthreads();

  const float t = sval[TOPK - 1];
  for (int i = tid; i < n; i += 256)
    if (cval[i] >= t) atomicAdd(&s_nsurv, 1);
  __syncthreads();
  const int nsurv = min(s_nsurv, SCAP);

  const float m = sval[0];
  for (int i = tid; i < nsurv; i += 256) pvals[i] = expf(sval[i] - m);
  __syncthreads();
  if (tid == 0) {
    float Z0 = 0.f;
    for (int i = 0; i < nsurv; ++i) Z0 += pvals[i];
    float cum = 0.f;
    int kc = 0;
    float Z2 = 0.f;
    for (int i = 0; i < nsurv; ++i) {
      cum += pvals[i] / Z0;
      if (cum > TOPP) break;
      kc = i + 1;
      Z2 += pvals[i];
    }
    s_kc = kc;
    s_invZ = (kc > 0) ? (1.f / Z2) : 0.f;
  }
  __syncthreads();
  const int kc = s_kc;
  const float invZ = s_invZ;

  for (int q = tid; q < kc; q += 256) {
    int r = -1, less = 0;
    for (int s = 0; s < nsurv; ++s) {
      if (sidx[s] == q) r = s;
      if (sidx[s] < q) ++less;
    }
    int rank = (r >= 0) ? r : (nsurv + q - less);
    rowp[rank] = pvals[q] * invZ;
  }
}

// ----------------------------- launcher ------------------------------
extern "C" void kernel_launch(void* const* d_in, const int* in_sizes, int n_in,
                              void* d_out, int out_size, void* d_ws, size_t ws_size,
                              hipStream_t stream) {
  const float* X = (const float*)d_in[0];
  const float* W = (const float*)d_in[1];
  const float* Bv = (const float*)d_in[2];
  float* C = (float*)d_out;

  unsigned short* Xp = (unsigned short*)d_ws;
  unsigned short* Wp = Xp + (size_t)M_TOT * KP;
  unsigned* Tmax = (unsigned*)(Wp + (size_t)NPAD2 * KP);

  convx_kernel<<<(M_TOT * (K_DIM / 4) + 255) / 256, 256, 0, stream>>>(X, Xp);
  convw_kernel<<<(NPAD2 * (K_DIM / 4) + 255) / 256, 256, 0, stream>>>(W, Wp);
  dim3 g(NBM2, NBN2);  // M fastest: consecutive blocks share a B panel
  gemm256_kernel<<<g, 512, 0, stream>>>(Xp, Wp, Bv, C, Tmax);
  select_kernel<<<M_TOT, 256, 0, stream>>>(C, Tmax);
}